// Round 1
// baseline (38361.807 us; speedup 1.0000x reference)
//
#include <hip/hip_runtime.h>
#include <cmath>

// ---------------- constants ----------------
static constexpr int QL_ = 512;   // qlen
static constexpr int KL_ = 1024;  // klen
static constexpr int BS_ = 16;    // bsz

// workspace offsets (in floats)
static constexpr size_t OFF_THEME = 0;                                   // 1000*1024
static constexpr size_t OFF_ROLE  = OFF_THEME + (size_t)1000*1024;       // 64*256
static constexpr size_t OFF_TCAT  = OFF_ROLE  + (size_t)64*256;          // 1000*512
static constexpr size_t OFF_POS   = OFF_TCAT  + (size_t)1000*512;        // 1024*1024
static constexpr size_t OFF_RH    = OFF_POS   + (size_t)1024*1024;       // 1024*1024
static constexpr size_t OFF_OUT   = OFF_RH    + (size_t)1024*1024;       // 512*16*1024
static constexpr size_t OFF_H     = OFF_OUT   + (size_t)512*16*1024;
static constexpr size_t OFF_T2    = OFF_H     + (size_t)512*16*1024;
static constexpr size_t OFF_VEC   = OFF_T2    + (size_t)512*16*1024;     // also LN1 output
static constexpr size_t OFF_POOL  = OFF_VEC   + (size_t)512*16*1024;     // 16*1024
static constexpr size_t OFF_HEADS = OFF_POOL  + (size_t)16*1024;         // 1024*16*3072 (also FFN1 buf)

// ---------------- small kernels ----------------
__global__ void k_role(const float* __restrict__ rel_r_f, const float* __restrict__ form_emb,
                       const float* __restrict__ role_emb, float* __restrict__ role)
{
    int r = blockIdx.x, c = threadIdx.x;
    float v;
    if (c < 128) v = role_emb[r*128 + c];
    else {
        v = 0.f; int cc = c - 128;
        #pragma unroll
        for (int k = 0; k < 32; ++k) v += rel_r_f[r*32 + k] * form_emb[k*128 + cc];
    }
    role[r*256 + c] = v;
}

__global__ void k_tcat(const float* __restrict__ rel_t_r, const float* __restrict__ role,
                       const float* __restrict__ theme_emb, float* __restrict__ tcat)
{
    int t = blockIdx.x, c = threadIdx.x;
    float v;
    if (c < 256) v = theme_emb[t*256 + c];
    else {
        v = 0.f; int cc = c - 256;
        for (int k = 0; k < 64; ++k) v += rel_t_r[t*64 + k] * role[k*256 + cc];
    }
    tcat[t*512 + c] = v;
}

__global__ void k_pos(float* __restrict__ pos)
{
    int gid = blockIdx.x*256 + threadIdx.x;   // 1024*1024 total
    int j = gid >> 10, dd = gid & 1023;
    float p = (float)(1023 - j);
    int x = (dd < 512) ? dd : (dd - 512);
    float invf = 1.0f / powf(10000.0f, (float)x * (1.0f/512.0f));
    float a = p * invf;
    pos[gid] = (dd < 512) ? sinf(a) : cosf(a);
}

__global__ void k_embed(const int* __restrict__ dec, const float* __restrict__ wemb,
                        float* __restrict__ out)
{
    int row = blockIdx.x;               // t*16+b
    int tok = dec[row];
    const float4 v = *(const float4*)(wemb + (size_t)tok*1024 + threadIdx.x*4);
    *(float4*)(out + (size_t)row*1024 + threadIdx.x*4) = v;
}

template<bool ADD>
__global__ void k_ln(const float* __restrict__ x, const float* __restrict__ y,
                     const float* __restrict__ g, const float* __restrict__ be,
                     float* __restrict__ o)
{
    __shared__ float red[256];
    const int row = blockIdx.x, tid = threadIdx.x;
    const size_t base = (size_t)row*1024 + tid*4;
    float4 xv = *(const float4*)(x + base);
    if (ADD) {
        float4 yv = *(const float4*)(y + base);
        xv.x += yv.x; xv.y += yv.y; xv.z += yv.z; xv.w += yv.w;
    }
    red[tid] = xv.x + xv.y + xv.z + xv.w;
    __syncthreads();
    for (int st = 128; st > 0; st >>= 1) { if (tid < st) red[tid] += red[tid+st]; __syncthreads(); }
    float mu = red[0] * (1.f/1024.f);
    __syncthreads();
    float dx = xv.x-mu, dy = xv.y-mu, dz = xv.z-mu, dw = xv.w-mu;
    red[tid] = dx*dx + dy*dy + dz*dz + dw*dw;
    __syncthreads();
    for (int st = 128; st > 0; st >>= 1) { if (tid < st) red[tid] += red[tid+st]; __syncthreads(); }
    float rstd = rsqrtf(red[0]*(1.f/1024.f) + 1e-3f);
    float4 gv = *(const float4*)(g + tid*4);
    float4 bv = *(const float4*)(be + tid*4);
    float4 ov;
    ov.x = dx*rstd*gv.x + bv.x;
    ov.y = dy*rstd*gv.y + bv.y;
    ov.z = dz*rstd*gv.z + bv.z;
    ov.w = dw*rstd*gv.w + bv.w;
    *(float4*)(o + base) = ov;
}

__global__ void k_pool(const int* __restrict__ dec, const float* __restrict__ out,
                       float* __restrict__ pooled)
{
    int gid = blockIdx.x*256 + threadIdx.x;   // 16*1024
    int b = gid >> 10, d = gid & 1023;
    float s = 0.f;
    for (int t = 0; t < 512; ++t) {
        float e = (dec[t*16 + b] == 2) ? 1.0f : 0.0f;
        s += e * out[((size_t)t*16 + b)*1024 + d];
    }
    pooled[gid] = s;
}

__global__ void k_logits(const float* __restrict__ pooled, const float* __restrict__ theme,
                         float* __restrict__ logits)
{
    int t = blockIdx.x;          // 1000 blocks, 64 threads
    int lane = threadIdx.x;
    float acc[16];
    #pragma unroll
    for (int b = 0; b < 16; ++b) acc[b] = 0.f;
    for (int d = lane; d < 1024; d += 64) {
        float tv = theme[(size_t)t*1024 + d];
        #pragma unroll
        for (int b = 0; b < 16; ++b) acc[b] += pooled[b*1024 + d] * tv;
    }
    #pragma unroll
    for (int b = 0; b < 16; ++b) {
        float v = acc[b];
        for (int m = 32; m >= 1; m >>= 1) v += __shfl_xor(v, m);
        if (lane == 0) logits[b*1000 + t] = v;
    }
}

// ---------------- fp32 GEMM: C[M,N] = act(A[M,K] @ B[K,N] + bias) ----------------
// 128x128 tile, Ktile=16, 256 threads, 8x8 per thread, XOR-swizzled k-major LDS.
__device__ __forceinline__ int gswz(int kk, int col) {
    return kk*128 + ((((col >> 2) ^ kk) << 2) | (col & 3));
}

template<int ACT, bool BIAS, bool CAT>
__launch_bounds__(256)
__global__ void gemm128(const float* __restrict__ A, const float* __restrict__ A2, int M1,
                        const float* __restrict__ B, const float* __restrict__ bias,
                        float* __restrict__ C, int M, int N, int K)
{
    __shared__ float As[16*128];
    __shared__ float Bs[16*128];
    const int tid = threadIdx.x;
    const int tx = tid & 15, ty = tid >> 4;
    const int n0 = blockIdx.x * 128, m0 = blockIdx.y * 128;

    float acc[8][8];
    #pragma unroll
    for (int q = 0; q < 8; ++q)
        #pragma unroll
        for (int p = 0; p < 8; ++p) acc[q][p] = 0.f;

    for (int k0 = 0; k0 < K; k0 += 16) {
        // stage A (transposed to k-major)
        #pragma unroll
        for (int rep = 0; rep < 2; ++rep) {
            int m  = (tid >> 2) + (rep << 6);
            int gm = m0 + m;
            int kk = (tid & 3) << 2;
            float4 av = make_float4(0.f, 0.f, 0.f, 0.f);
            if (gm < M) {
                const float* src = A; int rrow = gm;
                if (CAT) { if (gm >= M1) { src = A2; rrow = gm - M1; } }
                av = *(const float4*)(src + (size_t)rrow*K + k0 + kk);
            }
            As[gswz(kk+0, m)] = av.x;
            As[gswz(kk+1, m)] = av.y;
            As[gswz(kk+2, m)] = av.z;
            As[gswz(kk+3, m)] = av.w;
        }
        // stage B (already k-major)
        #pragma unroll
        for (int rep = 0; rep < 2; ++rep) {
            int c    = tid + (rep << 8);
            int kk   = c >> 5;
            int ncol = (c & 31) << 2;
            float4 bv = *(const float4*)(B + (size_t)(k0+kk)*N + n0 + ncol);
            *(float4*)(Bs + gswz(kk, ncol)) = bv;
        }
        __syncthreads();
        #pragma unroll
        for (int kk = 0; kk < 16; ++kk) {
            float a[8], bb[8];
            *(float4*)&a[0]  = *(const float4*)(As + gswz(kk, ty*8));
            *(float4*)&a[4]  = *(const float4*)(As + gswz(kk, ty*8+4));
            *(float4*)&bb[0] = *(const float4*)(Bs + gswz(kk, tx*8));
            *(float4*)&bb[4] = *(const float4*)(Bs + gswz(kk, tx*8+4));
            #pragma unroll
            for (int q = 0; q < 8; ++q)
                #pragma unroll
                for (int p = 0; p < 8; ++p) acc[q][p] += a[q] * bb[p];
        }
        __syncthreads();
    }

    float b8[8];
    if (BIAS) {
        *(float4*)&b8[0] = *(const float4*)(bias + n0 + tx*8);
        *(float4*)&b8[4] = *(const float4*)(bias + n0 + tx*8 + 4);
    }
    #pragma unroll
    for (int q = 0; q < 8; ++q) {
        int gm = m0 + ty*8 + q;
        if (gm >= M) continue;
        float ov[8];
        #pragma unroll
        for (int p = 0; p < 8; ++p) {
            float v = acc[q][p] + (BIAS ? b8[p] : 0.f);
            if (ACT == 1) v = tanhf(v);
            if (ACT == 2) v = fmaxf(v, 0.f);
            ov[p] = v;
        }
        *(float4*)(C + (size_t)gm*N + n0 + tx*8)     = *(float4*)&ov[0];
        *(float4*)(C + (size_t)gm*N + n0 + tx*8 + 4) = *(float4*)&ov[4];
    }
}

// ---------------- fused attention (flash-style, rel-shift folded) ----------------
// block: (i-tile of 32, b, n); 256 threads = 8 row-groups(4 rows) x 32 col-groups(2 cols)
__device__ __forceinline__ int swz(int row, int c4) {
    return row*64 + ((c4 ^ (row & 15)) << 2);
}

__launch_bounds__(256)
__global__ void k_attn(const float* __restrict__ heads, const float* __restrict__ rh,
                       const float* __restrict__ rwb, const float* __restrict__ rrb,
                       const int* __restrict__ dec, float* __restrict__ vec)
{
    __shared__ float qw[33*64];     // q + r_w_bias, rows i0..i0+32
    __shared__ float kv_s[64*64];   // K tile (score phase), then V tile (PV phase); swizzled
    __shared__ float rt[96*64];     // shifted rh rows (score), then P (PV); swizzled/plain
    __shared__ float dif[64];       // rrb - rwb
    float* ps = rt;

    const int i0  = blockIdx.x * 32;
    const int b   = blockIdx.y;
    const int n   = blockIdx.z;
    const int tid = threadIdx.x;
    const int tx  = tid & 31;       // cols 2tx, 2tx+1
    const int ty  = tid >> 5;       // rows 4ty..4ty+3

    // stage qw (+ bias diff)
    for (int idx = tid; idx < 33*16; idx += 256) {
        int r = idx >> 4, c4 = idx & 15;
        int iq = i0 + r; if (iq > 511) iq = 511;
        float4 qv = *(const float4*)(heads + ((size_t)(512 + iq)*16 + b)*3072 + n*64 + (c4<<2));
        float4 wv = *(const float4*)(rwb + n*64 + (c4<<2));
        qv.x += wv.x; qv.y += wv.y; qv.z += wv.z; qv.w += wv.w;
        *(float4*)(qw + r*64 + (c4<<2)) = qv;
    }
    if (tid < 16) {
        float4 a = *(const float4*)(rrb + n*64 + (tid<<2));
        float4 c = *(const float4*)(rwb + n*64 + (tid<<2));
        a.x -= c.x; a.y -= c.y; a.z -= c.z; a.w -= c.w;
        *(float4*)(dif + (tid<<2)) = a;
    }

    float m_run[4], l_run[4], acc[4][2];
    #pragma unroll
    for (int q = 0; q < 4; ++q) { m_run[q] = -3.0e38f; l_run[q] = 0.f; acc[q][0] = 0.f; acc[q][1] = 0.f; }

    const int rbase = 2*tx - 4*ty + 28;

    for (int j0 = 0; j0 < 1024; j0 += 64) {
        __syncthreads();
        // stage K tile
        for (int idx = tid; idx < 64*16; idx += 256) {
            int jj = idx >> 4, c4 = idx & 15;
            float4 v = *(const float4*)(heads + ((size_t)(j0+jj)*16 + b)*3072 + 1024 + n*64 + (c4<<2));
            *(float4*)(kv_s + swz(jj, c4)) = v;
        }
        // stage shifted-rh tile: row rr holds rh for u = umin+rr (0 where rel_shift pads)
        const int umin = j0 - i0 - 31;
        for (int idx = tid; idx < 96*16; idx += 256) {
            int rr = idx >> 4, c4 = idx & 15;
            int u  = umin + rr;
            int jr = (u <= 512) ? (511 + u) : (u - 514);   // u==513 -> -1 -> zeros
            float4 v = make_float4(0.f, 0.f, 0.f, 0.f);
            if (jr >= 0 && jr < 1024)
                v = *(const float4*)(rh + (size_t)jr*1024 + n*64 + (c4<<2));
            *(float4*)(rt + swz(rr, c4)) = v;
        }
        __syncthreads();

        // scores: AC + BD
        float s0[4][2];
        #pragma unroll
        for (int q = 0; q < 4; ++q) { s0[q][0] = 0.f; s0[q][1] = 0.f; }
        const int u00 = (j0 + 2*tx) - (i0 + 4*ty);
        for (int c4 = 0; c4 < 16; ++c4) {
            float4 dv = *(const float4*)(dif + (c4<<2));
            float4 qv[5], qr[5];
            #pragma unroll
            for (int s5 = 0; s5 < 5; ++s5) {
                qv[s5] = *(const float4*)(qw + (4*ty+s5)*64 + (c4<<2));
                qr[s5].x = qv[s5].x + dv.x; qr[s5].y = qv[s5].y + dv.y;
                qr[s5].z = qv[s5].z + dv.z; qr[s5].w = qv[s5].w + dv.w;
            }
            float4 kk[2];
            kk[0] = *(const float4*)(kv_s + swz(2*tx,   c4));
            kk[1] = *(const float4*)(kv_s + swz(2*tx+1, c4));
            float4 rv[5];
            #pragma unroll
            for (int s5 = 0; s5 < 5; ++s5) rv[s5] = *(const float4*)(rt + swz(rbase + s5, c4));
            #pragma unroll
            for (int q = 0; q < 4; ++q) {
                #pragma unroll
                for (int p = 0; p < 2; ++p) {
                    float ac = qv[q].x*kk[p].x + qv[q].y*kk[p].y + qv[q].z*kk[p].z + qv[q].w*kk[p].w;
                    int u = u00 + p - q;
                    float4 qq = (u >= 514) ? qr[q+1] : qr[q];
                    float4 rr2 = rv[p - q + 3];
                    float bd = qq.x*rr2.x + qq.y*rr2.y + qq.z*rr2.z + qq.w*rr2.w;
                    s0[q][p] += ac + bd;
                }
            }
        }
        // scale + key mask
        float sc[4][2];
        #pragma unroll
        for (int p = 0; p < 2; ++p) {
            int j = j0 + 2*tx + p;
            bool masked = (j >= 512) && (dec[(j-512)*16 + b] == 0);
            #pragma unroll
            for (int q = 0; q < 4; ++q) sc[q][p] = masked ? -1.0e9f : s0[q][p] * 0.125f;
        }
        __syncthreads();   // K/rh reads done -> reuse LDS
        // stage V tile into kv_s
        for (int idx = tid; idx < 64*16; idx += 256) {
            int jj = idx >> 4, c4 = idx & 15;
            float4 v = *(const float4*)(heads + ((size_t)(j0+jj)*16 + b)*3072 + 2048 + n*64 + (c4<<2));
            *(float4*)(kv_s + swz(jj, c4)) = v;
        }
        // online softmax; write P into ps (rt region, plain layout)
        #pragma unroll
        for (int q = 0; q < 4; ++q) {
            float tmax = fmaxf(sc[q][0], sc[q][1]);
            for (int msk = 16; msk >= 1; msk >>= 1) tmax = fmaxf(tmax, __shfl_xor(tmax, msk));
            float mnew  = fmaxf(m_run[q], tmax);
            float alpha = expf(m_run[q] - mnew);
            float p0 = expf(sc[q][0] - mnew);
            float p1 = expf(sc[q][1] - mnew);
            float tsum = p0 + p1;
            for (int msk = 16; msk >= 1; msk >>= 1) tsum += __shfl_xor(tsum, msk);
            l_run[q] = l_run[q]*alpha + tsum;
            m_run[q] = mnew;
            acc[q][0] *= alpha; acc[q][1] *= alpha;
            *(float2*)(ps + (4*ty+q)*64 + 2*tx) = make_float2(p0, p1);
        }
        __syncthreads();
        // PV
        for (int j = 0; j < 64; ++j) {
            float2 vv = *(const float2*)(kv_s + swz(j, tx >> 1) + ((2*tx) & 3));
            #pragma unroll
            for (int q = 0; q < 4; ++q) {
                float pq = ps[(4*ty+q)*64 + j];
                acc[q][0] += pq * vv.x;
                acc[q][1] += pq * vv.y;
            }
        }
    }
    #pragma unroll
    for (int q = 0; q < 4; ++q) {
        int i = i0 + 4*ty + q;
        float inv = 1.0f / l_run[q];
        *(float2*)(vec + ((size_t)i*16 + b)*1024 + n*64 + 2*tx) =
            make_float2(acc[q][0]*inv, acc[q][1]*inv);
    }
}

// ---------------- launch ----------------
extern "C" void kernel_launch(void* const* d_in, const int* in_sizes, int n_in,
                              void* d_out, int out_size, void* d_ws, size_t ws_size,
                              hipStream_t stream)
{
    (void)in_sizes; (void)n_in; (void)out_size; (void)ws_size;
    const int*   dec       = (const int*)  d_in[0];
    const float* mems      = (const float*)d_in[1];
    const float* rel_t_r   = (const float*)d_in[2];
    const float* rel_r_f   = (const float*)d_in[3];
    const float* theme_emb = (const float*)d_in[4];
    const float* role_emb  = (const float*)d_in[5];
    const float* form_emb  = (const float*)d_in[6];
    const float* word_emb  = (const float*)d_in[7];
    const float* theme_W   = (const float*)d_in[8];
    const float* theme_b   = (const float*)d_in[9];
    const float* r_w_bias  = (const float*)d_in[10];
    const float* r_r_bias  = (const float*)d_in[11];
    const float* qkv_W     = (const float*)d_in[12];
    const float* qkv_b     = (const float*)d_in[13];
    const float* r_W       = (const float*)d_in[14];
    const float* o_W       = (const float*)d_in[15];
    const float* o_b       = (const float*)d_in[16];
    const float* ln_att_g  = (const float*)d_in[17];
    const float* ln_att_b  = (const float*)d_in[18];
    const float* ln1_g     = (const float*)d_in[19];
    const float* ln1_b     = (const float*)d_in[20];
    const float* ffn_W1    = (const float*)d_in[21];
    const float* ffn_b1    = (const float*)d_in[22];
    const float* ffn_W2    = (const float*)d_in[23];
    const float* ffn_b2    = (const float*)d_in[24];
    const float* ln2_g     = (const float*)d_in[25];
    const float* ln2_b     = (const float*)d_in[26];

    float* ws      = (float*)d_ws;
    float* logits  = (float*)d_out;
    float* w_theme = ws + OFF_THEME;
    float* w_role  = ws + OFF_ROLE;
    float* w_tcat  = ws + OFF_TCAT;
    float* w_pos   = ws + OFF_POS;
    float* w_rh    = ws + OFF_RH;
    float* w_out   = ws + OFF_OUT;
    float* w_h     = ws + OFF_H;
    float* w_t2    = ws + OFF_T2;
    float* w_vec   = ws + OFF_VEC;
    float* w_pool  = ws + OFF_POOL;
    float* w_heads = ws + OFF_HEADS;

    // theme pipeline
    k_role<<<64, 256, 0, stream>>>(rel_r_f, form_emb, role_emb, w_role);
    k_tcat<<<1000, 512, 0, stream>>>(rel_t_r, w_role, theme_emb, w_tcat);
    gemm128<1, true, false><<<dim3(8, 8), 256, 0, stream>>>(
        w_tcat, nullptr, 0, theme_W, theme_b, w_theme, 1000, 1024, 512);

    k_pos<<<4096, 256, 0, stream>>>(w_pos);
    k_embed<<<8192, 256, 0, stream>>>(dec, word_emb, w_out);

    for (int i = 0; i < 8; ++i) {
        const float* memi = mems + (size_t)i*512*16*1024;
        // QKV (concat(mems, out) fused into A-load)
        gemm128<0, true, true><<<dim3(24, 128), 256, 0, stream>>>(
            memi, w_out, 8192, qkv_W + (size_t)i*1024*3072, qkv_b + (size_t)i*3072,
            w_heads, 16384, 3072, 1024);
        // rh = pos @ r_W
        gemm128<0, false, false><<<dim3(8, 8), 256, 0, stream>>>(
            w_pos, nullptr, 0, r_W + (size_t)i*1024*1024, nullptr, w_rh, 1024, 1024, 1024);
        // fused attention -> vec
        k_attn<<<dim3(16, 16, 16), 256, 0, stream>>>(w_heads, w_rh, r_w_bias, r_r_bias, dec, w_vec);
        // out-proj
        gemm128<0, true, false><<<dim3(8, 64), 256, 0, stream>>>(
            w_vec, nullptr, 0, o_W + (size_t)i*1024*1024, o_b + (size_t)i*1024,
            w_t2, 8192, 1024, 1024);
        // h = LN(out + att)
        k_ln<true><<<8192, 256, 0, stream>>>(w_out, w_t2, ln_att_g + i*1024, ln_att_b + i*1024, w_h);
        // t = LN(h)   (reuse vec buffer)
        k_ln<false><<<8192, 256, 0, stream>>>(w_h, nullptr, ln1_g + i*1024, ln1_b + i*1024, w_vec);
        // FFN1 (relu) into heads buffer
        gemm128<2, true, false><<<dim3(32, 64), 256, 0, stream>>>(
            w_vec, nullptr, 0, ffn_W1 + (size_t)i*1024*4096, ffn_b1 + (size_t)i*4096,
            w_heads, 8192, 4096, 1024);
        // FFN2
        gemm128<0, true, false><<<dim3(8, 64), 256, 0, stream>>>(
            w_heads, nullptr, 0, ffn_W2 + (size_t)i*4096*1024, ffn_b2 + (size_t)i*1024,
            w_t2, 8192, 1024, 4096);
        // out = LN(h + t)
        k_ln<true><<<8192, 256, 0, stream>>>(w_h, w_t2, ln2_g + i*1024, ln2_b + i*1024, w_out);
    }

    k_pool<<<64, 256, 0, stream>>>(dec, w_out, w_pool);
    k_logits<<<1000, 64, 0, stream>>>(w_pool, w_theme, logits);
}